// Round 10
// baseline (192.584 us; speedup 1.0000x reference)
//
#include <hip/hip_runtime.h>

#define D 2048
#define M 512

// Tuned NS coefficients, equioscillation on sv interval [0.48,1.52]:
// step1 -> delta 0.2188, step2 -> 0.03633, step3 -> 0.00099
#define CA1 1.7509363f
#define CB1 0.5353890f
#define CA2 1.5424421f
#define CB2 0.5060067f
#define CA3 1.5011558f
#define CB3 0.5001653f

typedef __attribute__((ext_vector_type(8))) short bf16x8;
typedef __attribute__((ext_vector_type(4))) float f32x4;

__device__ inline unsigned short f2bf(float f) {
    union { float f; unsigned u; } v; v.f = f;
    unsigned r = v.u + 0x7fffu + ((v.u >> 16) & 1u);  // RNE
    return (unsigned short)(r >> 16);
}
__device__ inline float bf2f(unsigned short h) {
    union { float f; unsigned u; } v; v.u = ((unsigned)h) << 16;
    return v.f;
}
__device__ inline uint2 pack4(const unsigned short* h) {
    uint2 u;
    u.x = h[0] | ((unsigned)h[1] << 16);
    u.y = h[2] | ((unsigned)h[3] << 16);
    return u;
}

// per-wave K-range fragment MACs into acc pair (split-bf16 3-MFMA scheme)
__device__ inline void mm_ks(const unsigned short* __restrict__ aHi,
                             const unsigned short* __restrict__ aLo, int lda,
                             const unsigned short* __restrict__ bHi,
                             const unsigned short* __restrict__ bLo, int ldb,
                             int K, int lm, int lq, f32x4& a1, f32x4& a2) {
    const unsigned short* ah = aHi + (size_t)lm * lda + lq * 8;
    const unsigned short* al = aLo + (size_t)lm * lda + lq * 8;
    const unsigned short* bh = bHi + (size_t)lm * ldb + lq * 8;
    const unsigned short* bl = bLo + (size_t)lm * ldb + lq * 8;
    #pragma unroll 4
    for (int k = 0; k < K; k += 32) {
        const bf16x8 fah = *(const bf16x8*)(ah + k);
        const bf16x8 fal = *(const bf16x8*)(al + k);
        const bf16x8 fbh = *(const bf16x8*)(bh + k);
        const bf16x8 fbl = *(const bf16x8*)(bl + k);
        a1 = __builtin_amdgcn_mfma_f32_16x16x32_bf16(fah, fbh, a1, 0, 0, 0);
        a2 = __builtin_amdgcn_mfma_f32_16x16x32_bf16(fah, fbl, a2, 0, 0, 0);
        a2 = __builtin_amdgcn_mfma_f32_16x16x32_bf16(fal, fbh, a2, 0, 0, 0);
    }
}

// 4-wave split-K reduce through LDS; returns element (row=t>>4, col=t&15).
__device__ inline float splitk_reduce(float* red, const f32x4& s,
                                      int w, int lm, int lq, int t) {
    #pragma unroll
    for (int r = 0; r < 4; ++r) red[w * 256 + (lq * 4 + r) * 16 + lm] = s[r];
    __syncthreads();
    return red[t] + red[256 + t] + red[512 + t] + red[768 + t];
}

// ---- d1: X fp32 (D x M) -> Xhi/Xlo (row-major) + XThi/XTlo (M x D), LDS-tiled
__global__ __launch_bounds__(256) void trans_split(
    const float* __restrict__ X,
    unsigned short* __restrict__ Xhi, unsigned short* __restrict__ Xlo,
    unsigned short* __restrict__ XThi, unsigned short* __restrict__ XTlo) {
    __shared__ unsigned short Lh[64 * 72], Ll[64 * 72];
    const int dBase = blockIdx.x * 64;
    const int mBase = blockIdx.y * 64;
    const int t = threadIdx.x;
    const int dl = t >> 4;
    const int ml = (t & 15) * 4;
    #pragma unroll
    for (int i = 0; i < 4; ++i) {
        const int d = i * 16 + dl;
        const float4 v4 = *(const float4*)(X + (size_t)(dBase + d) * M + mBase + ml);
        const float v[4] = {v4.x, v4.y, v4.z, v4.w};
        unsigned short hi[4], lo[4];
        #pragma unroll
        for (int j = 0; j < 4; ++j) { hi[j] = f2bf(v[j]); lo[j] = f2bf(v[j] - bf2f(hi[j])); }
        *(uint2*)(Xhi + (size_t)(dBase + d) * M + mBase + ml) = pack4(hi);
        *(uint2*)(Xlo + (size_t)(dBase + d) * M + mBase + ml) = pack4(lo);
        #pragma unroll
        for (int j = 0; j < 4; ++j) { Lh[(ml + j) * 72 + d] = hi[j]; Ll[(ml + j) * 72 + d] = lo[j]; }
    }
    __syncthreads();
    const int m = t >> 2;
    const int dd = (t & 3) * 16;
    const uint4 h0 = *(const uint4*)(Lh + m * 72 + dd);
    const uint4 h1 = *(const uint4*)(Lh + m * 72 + dd + 8);
    const uint4 l0 = *(const uint4*)(Ll + m * 72 + dd);
    const uint4 l1 = *(const uint4*)(Ll + m * 72 + dd + 8);
    unsigned short* th = XThi + (size_t)(mBase + m) * D + dBase + dd;
    unsigned short* tl = XTlo + (size_t)(mBase + m) * D + dBase + dd;
    *(uint4*)th = h0; *(uint4*)(th + 8) = h1;
    *(uint4*)tl = l0; *(uint4*)(tl + 8) = l1;
}

// ---- d2: G0 = X^T X (block/tile, 4-wave split-K over 2048); emit G0, C1.
__global__ __launch_bounds__(256) void gram_c(
    const unsigned short* __restrict__ XThi, const unsigned short* __restrict__ XTlo,
    unsigned short* __restrict__ Gh, unsigned short* __restrict__ Gl,
    unsigned short* __restrict__ Ch, unsigned short* __restrict__ Cl) {
    __shared__ float red[1024];
    const int tile = blockIdx.x;
    const int i0 = (tile >> 5) * 16, j0 = (tile & 31) * 16;
    const int t = threadIdx.x, w = t >> 6, lane = t & 63;
    const int lm = lane & 15, lq = lane >> 4;
    const size_t ko = (size_t)w * 512;
    f32x4 a1 = {0.f, 0.f, 0.f, 0.f}, a2 = {0.f, 0.f, 0.f, 0.f};
    mm_ks(XThi + (size_t)i0 * D + ko, XTlo + (size_t)i0 * D + ko, D,
          XThi + (size_t)j0 * D + ko, XTlo + (size_t)j0 * D + ko, D,
          512, lm, lq, a1, a2);
    const float g = splitk_reduce(red, a1 + a2, w, lm, lq, t);
    const int row = i0 + (t >> 4), col = j0 + (t & 15);
    const size_t idx = (size_t)row * M + col;
    unsigned short h = f2bf(g);
    Gh[idx] = h; Gl[idx] = f2bf(g - bf2f(h));
    const float c = (row == col ? CA1 : 0.0f) - CB1 * g;
    h = f2bf(c);
    Ch[idx] = h; Cl[idx] = f2bf(c - bf2f(h));
}

// ---- d3: O = U·V (V symmetric). Block/tile, split-K=4 over 512.
__global__ __launch_bounds__(256) void mm_small(
    const unsigned short* __restrict__ Uh, const unsigned short* __restrict__ Ul,
    const unsigned short* __restrict__ Vh, const unsigned short* __restrict__ Vl,
    unsigned short* __restrict__ Oh, unsigned short* __restrict__ Ol) {
    __shared__ float red[1024];
    const int tile = blockIdx.x;
    const int i0 = (tile >> 5) * 16, j0 = (tile & 31) * 16;
    const int t = threadIdx.x, w = t >> 6, lane = t & 63;
    const int lm = lane & 15, lq = lane >> 4;
    const size_t ko = (size_t)w * 128;
    f32x4 a1 = {0.f, 0.f, 0.f, 0.f}, a2 = {0.f, 0.f, 0.f, 0.f};
    mm_ks(Uh + (size_t)i0 * M + ko, Ul + (size_t)i0 * M + ko, M,
          Vh + (size_t)j0 * M + ko, Vl + (size_t)j0 * M + ko, M,
          128, lm, lq, a1, a2);
    const float v = splitk_reduce(red, a1 + a2, w, lm, lq, t);
    const size_t idx = (size_t)(i0 + (t >> 4)) * M + j0 + (t & 15);
    const unsigned short h = f2bf(v);
    Oh[idx] = h; Ol[idx] = f2bf(v - bf2f(h));
}

// ---- d5: dual small mm: job0: O0 = U0·V0; job1: O1 = U1·V1.
__global__ __launch_bounds__(256) void mm_dual(
    const unsigned short* __restrict__ U0h, const unsigned short* __restrict__ U0l,
    const unsigned short* __restrict__ V0h, const unsigned short* __restrict__ V0l,
    unsigned short* __restrict__ O0h, unsigned short* __restrict__ O0l,
    const unsigned short* __restrict__ U1h, const unsigned short* __restrict__ U1l,
    const unsigned short* __restrict__ V1h, const unsigned short* __restrict__ V1l,
    unsigned short* __restrict__ O1h, unsigned short* __restrict__ O1l) {
    __shared__ float red[1024];
    const int unit = blockIdx.x;
    const int job = unit >> 10, tile = unit & 1023;
    const int i0 = (tile >> 5) * 16, j0 = (tile & 31) * 16;
    const int t = threadIdx.x, w = t >> 6, lane = t & 63;
    const int lm = lane & 15, lq = lane >> 4;
    const size_t ko = (size_t)w * 128;
    const unsigned short* Uh = job ? U1h : U0h;
    const unsigned short* Ul = job ? U1l : U0l;
    const unsigned short* Vh = job ? V1h : V0h;
    const unsigned short* Vl = job ? V1l : V0l;
    unsigned short* Oh = job ? O1h : O0h;
    unsigned short* Ol = job ? O1l : O0l;
    f32x4 a1 = {0.f, 0.f, 0.f, 0.f}, a2 = {0.f, 0.f, 0.f, 0.f};
    mm_ks(Uh + (size_t)i0 * M + ko, Ul + (size_t)i0 * M + ko, M,
          Vh + (size_t)j0 * M + ko, Vl + (size_t)j0 * M + ko, M,
          128, lm, lq, a1, a2);
    const float v = splitk_reduce(red, a1 + a2, w, lm, lq, t);
    const size_t idx = (size_t)(i0 + (t >> 4)) * M + j0 + (t & 15);
    const unsigned short h = f2bf(v);
    Oh[idx] = h; Ol[idx] = f2bf(v - bf2f(h));
}

// ---- d4: W = U·V; P = cA*Ge + cB*Se + cC*W; store P (opt) and C = a*I - b*P.
__global__ __launch_bounds__(256) void mm_poly(
    const unsigned short* __restrict__ Uh, const unsigned short* __restrict__ Ul,
    const unsigned short* __restrict__ Vh, const unsigned short* __restrict__ Vl,
    const unsigned short* __restrict__ Geh, const unsigned short* __restrict__ Gel,
    const unsigned short* __restrict__ Seh, const unsigned short* __restrict__ Sel,
    unsigned short* __restrict__ Ph, unsigned short* __restrict__ Pl,
    unsigned short* __restrict__ Ch, unsigned short* __restrict__ Cl,
    const float cA, const float cB, const float cC,
    const float a, const float b, const int writeP) {
    __shared__ float red[1024];
    const int tile = blockIdx.x;
    const int i0 = (tile >> 5) * 16, j0 = (tile & 31) * 16;
    const int t = threadIdx.x, w = t >> 6, lane = t & 63;
    const int lm = lane & 15, lq = lane >> 4;
    const size_t ko = (size_t)w * 128;
    f32x4 a1 = {0.f, 0.f, 0.f, 0.f}, a2 = {0.f, 0.f, 0.f, 0.f};
    mm_ks(Uh + (size_t)i0 * M + ko, Ul + (size_t)i0 * M + ko, M,
          Vh + (size_t)j0 * M + ko, Vl + (size_t)j0 * M + ko, M,
          128, lm, lq, a1, a2);
    const float wv = splitk_reduce(red, a1 + a2, w, lm, lq, t);
    const int row = i0 + (t >> 4), col = j0 + (t & 15);
    const size_t idx = (size_t)row * M + col;
    const float p = cA * (bf2f(Geh[idx]) + bf2f(Gel[idx]))
                  + cB * (bf2f(Seh[idx]) + bf2f(Sel[idx]))
                  + cC * wv;
    if (writeP) {
        const unsigned short h = f2bf(p);
        Ph[idx] = h; Pl[idx] = f2bf(p - bf2f(h));
    }
    const float c = (row == col ? a : 0.0f) - b * p;
    const unsigned short h2 = f2bf(c);
    Ch[idx] = h2; Cl[idx] = f2bf(c - bf2f(h2));
}

// ---- d6: blocks 0..1023: G2-poly -> C3 only; blocks 1024..5119: Y = X·B2.
__global__ __launch_bounds__(256) void poly_y(
    const unsigned short* __restrict__ G1h, const unsigned short* __restrict__ G1l,
    const unsigned short* __restrict__ S1h, const unsigned short* __restrict__ S1l,
    unsigned short* __restrict__ C3h, unsigned short* __restrict__ C3l,
    const unsigned short* __restrict__ Xhi, const unsigned short* __restrict__ Xlo,
    const unsigned short* __restrict__ B2h, const unsigned short* __restrict__ B2l,
    unsigned short* __restrict__ Yh, unsigned short* __restrict__ Yl) {
    __shared__ float red[1024];
    const int t = threadIdx.x, w = t >> 6, lane = t & 63;
    const int lm = lane & 15, lq = lane >> 4;
    const size_t ko = (size_t)w * 128;
    f32x4 a1 = {0.f, 0.f, 0.f, 0.f}, a2 = {0.f, 0.f, 0.f, 0.f};
    if (blockIdx.x < 1024) {
        const int tile = blockIdx.x;
        const int i0 = (tile >> 5) * 16, j0 = (tile & 31) * 16;
        mm_ks(G1h + (size_t)i0 * M + ko, G1l + (size_t)i0 * M + ko, M,
              S1h + (size_t)j0 * M + ko, S1l + (size_t)j0 * M + ko, M,
              128, lm, lq, a1, a2);
        const float wv = splitk_reduce(red, a1 + a2, w, lm, lq, t);
        const int row = i0 + (t >> 4), col = j0 + (t & 15);
        const size_t idx = (size_t)row * M + col;
        const float p = (CA2 * CA2) * (bf2f(G1h[idx]) + bf2f(G1l[idx]))
                      + (-2.0f * CA2 * CB2) * (bf2f(S1h[idx]) + bf2f(S1l[idx]))
                      + (CB2 * CB2) * wv;
        const float c = (row == col ? CA3 : 0.0f) - CB3 * p;
        const unsigned short h = f2bf(c);
        C3h[idx] = h; C3l[idx] = f2bf(c - bf2f(h));
    } else {
        const int tile = blockIdx.x - 1024;            // 0..4095 (128 x 32)
        const int i0 = (tile >> 5) * 16, j0 = (tile & 31) * 16;
        mm_ks(Xhi + (size_t)i0 * M + ko, Xlo + (size_t)i0 * M + ko, M,
              B2h + (size_t)j0 * M + ko, B2l + (size_t)j0 * M + ko, M,
              128, lm, lq, a1, a2);
        const float v = splitk_reduce(red, a1 + a2, w, lm, lq, t);
        const size_t idx = (size_t)(i0 + (t >> 4)) * M + j0 + (t & 15);
        const unsigned short h = f2bf(v);
        Yh[idx] = h; Yl[idx] = f2bf(v - bf2f(h));
    }
}

// ---- d7: out = Y·C3 (fp32). 4096 blocks, block/tile split-K=4.
__global__ __launch_bounds__(256) void final_mm(
    const unsigned short* __restrict__ Yh, const unsigned short* __restrict__ Yl,
    const unsigned short* __restrict__ Ch, const unsigned short* __restrict__ Cl,
    float* __restrict__ out) {
    __shared__ float red[1024];
    const int tile = blockIdx.x;                       // 0..4095 (128 x 32)
    const int i0 = (tile >> 5) * 16, j0 = (tile & 31) * 16;
    const int t = threadIdx.x, w = t >> 6, lane = t & 63;
    const int lm = lane & 15, lq = lane >> 4;
    const size_t ko = (size_t)w * 128;
    f32x4 a1 = {0.f, 0.f, 0.f, 0.f}, a2 = {0.f, 0.f, 0.f, 0.f};
    mm_ks(Yh + (size_t)i0 * M + ko, Yl + (size_t)i0 * M + ko, M,
          Ch + (size_t)j0 * M + ko, Cl + (size_t)j0 * M + ko, M,
          128, lm, lq, a1, a2);
    const float v = splitk_reduce(red, a1 + a2, w, lm, lq, t);
    out[(size_t)(i0 + (t >> 4)) * M + j0 + (t & 15)] = v;
}

extern "C" void kernel_launch(void* const* d_in, const int* in_sizes, int n_in,
                              void* d_out, int out_size, void* d_ws, size_t ws_size,
                              hipStream_t stream) {
    const float* Xin = (const float*)d_in[0];
    float* out = (float*)d_out;
    unsigned short* w = (unsigned short*)d_ws;

    unsigned short* Xhi  = w;                   // D*M = 1048576 each
    unsigned short* Xlo  = w + 1048576u;
    unsigned short* XThi = w + 2097152u;        // dead after d2 -> reused as Y
    unsigned short* XTlo = w + 3145728u;
    unsigned short* Yh   = XThi;                // D*M, overlays XT
    unsigned short* Yl   = XTlo;
    unsigned short* q = w + 4194304u;           // M*M = 262144 each below
    unsigned short* G0h = q;            unsigned short* G0l = q + 262144u;
    unsigned short* Sh  = q + 524288u;  unsigned short* Sl  = q + 786432u;
    unsigned short* G1h = q + 1048576u; unsigned short* G1l = q + 1310720u;
    unsigned short* S1h = q + 1572864u; unsigned short* S1l = q + 1835008u;
    unsigned short* C1h = q + 2097152u; unsigned short* C1l = q + 2359296u;
    unsigned short* C2h = q + 2621440u; unsigned short* C2l = q + 2883584u;
    unsigned short* C3h = q + 3145728u; unsigned short* C3l = q + 3407872u;
    unsigned short* B2h = q + 3670016u; unsigned short* B2l = q + 3932160u;

    // d1: split + transpose
    trans_split<<<dim3(32, 8), 256, 0, stream>>>(Xin, Xhi, Xlo, XThi, XTlo);
    // d2: G0 = X^T X ; C1 = CA1 I - CB1 G0
    gram_c<<<1024, 256, 0, stream>>>(XThi, XTlo, G0h, G0l, C1h, C1l);
    // d3: S = G0^2
    mm_small<<<1024, 256, 0, stream>>>(G0h, G0l, G0h, G0l, Sh, Sl);
    // d4: G1 = CA1^2 G0 - 2 CA1 CB1 S + CB1^2 (G0·S) ; C2 = CA2 I - CB2 G1
    mm_poly<<<1024, 256, 0, stream>>>(G0h, G0l, Sh, Sl, G0h, G0l, Sh, Sl,
                                      G1h, G1l, C2h, C2l,
                                      CA1 * CA1, -2.0f * CA1 * CB1, CB1 * CB1,
                                      CA2, CB2, 1);
    // d5: S1 = G1^2  ||  B2 = C1·C2
    mm_dual<<<2048, 256, 0, stream>>>(G1h, G1l, G1h, G1l, S1h, S1l,
                                      C1h, C1l, C2h, C2l, B2h, B2l);
    // d6: C3 from G2-poly  ||  Y = X·B2   (Y overlays dead XT)
    poly_y<<<5120, 256, 0, stream>>>(G1h, G1l, S1h, S1l, C3h, C3l,
                                     Xhi, Xlo, B2h, B2l, Yh, Yl);
    // d7: out = Y·C3
    final_mm<<<4096, 256, 0, stream>>>(Yh, Yl, C3h, C3l, out);
}

// Round 11
// 173.513 us; speedup vs baseline: 1.1099x; 1.1099x over previous
//
#include <hip/hip_runtime.h>

#define D 2048
#define M 512

// Tuned NS coefficients, equioscillation on sv interval [0.48,1.52]:
// step1 -> delta 0.2188, step2 -> 0.03633, step3 -> 0.00099
#define CA1 1.7509363f
#define CB1 0.5353890f
#define CA2 1.5424421f
#define CB2 0.5060067f
#define CA3 1.5011558f
#define CB3 0.5001653f

typedef unsigned short u16;
typedef __attribute__((ext_vector_type(8))) short bf16x8;
typedef __attribute__((ext_vector_type(4))) float f32x4;

__device__ inline u16 f2bf(float f) {
    union { float f; unsigned u; } v; v.f = f;
    unsigned r = v.u + 0x7fffu + ((v.u >> 16) & 1u);  // RNE
    return (u16)(r >> 16);
}
__device__ inline float bf2f(u16 h) {
    union { float f; unsigned u; } v; v.u = ((unsigned)h) << 16;
    return v.f;
}
__device__ inline uint2 pack4(const u16* h) {
    uint2 u;
    u.x = h[0] | ((unsigned)h[1] << 16);
    u.y = h[2] | ((unsigned)h[3] << 16);
    return u;
}

// per-wave K-range fragment MACs into acc pair (split-bf16 3-MFMA scheme)
__device__ inline void mm_ks(const u16* __restrict__ aHi,
                             const u16* __restrict__ aLo, int lda,
                             const u16* __restrict__ bHi,
                             const u16* __restrict__ bLo, int ldb,
                             int K, int lm, int lq, f32x4& a1, f32x4& a2) {
    const u16* ah = aHi + (size_t)lm * lda + lq * 8;
    const u16* al = aLo + (size_t)lm * lda + lq * 8;
    const u16* bh = bHi + (size_t)lm * ldb + lq * 8;
    const u16* bl = bLo + (size_t)lm * ldb + lq * 8;
    #pragma unroll 4
    for (int k = 0; k < K; k += 32) {
        const bf16x8 fah = *(const bf16x8*)(ah + k);
        const bf16x8 fal = *(const bf16x8*)(al + k);
        const bf16x8 fbh = *(const bf16x8*)(bh + k);
        const bf16x8 fbl = *(const bf16x8*)(bl + k);
        a1 = __builtin_amdgcn_mfma_f32_16x16x32_bf16(fah, fbh, a1, 0, 0, 0);
        a2 = __builtin_amdgcn_mfma_f32_16x16x32_bf16(fah, fbl, a2, 0, 0, 0);
        a2 = __builtin_amdgcn_mfma_f32_16x16x32_bf16(fal, fbh, a2, 0, 0, 0);
    }
}

// 32x32 tile of U·V per 512-thread block: 8 waves = 4 quadrants x 2 K-halves.
// LDS pair-reduce; each thread returns 2 elements (val/row/col).
// red must be float[2048]. K/2 must be a multiple of 32.
__device__ inline void tile32(const u16* __restrict__ Uh, const u16* __restrict__ Ul, int lda,
                              const u16* __restrict__ Vh, const u16* __restrict__ Vl, int ldb,
                              int K, int i0, int j0, int t, float* red,
                              float val[2], int row[2], int col[2]) {
    const int w = t >> 6, lane = t & 63;
    const int lm = lane & 15, lq = lane >> 4;
    const int q = w >> 1, kh = w & 1;
    const int qi = q >> 1, qj = q & 1;
    const int Kh = K >> 1;
    const size_t ko = (size_t)kh * Kh;
    f32x4 a1 = {0.f, 0.f, 0.f, 0.f}, a2 = {0.f, 0.f, 0.f, 0.f};
    mm_ks(Uh + (size_t)(i0 + 16 * qi) * lda + ko, Ul + (size_t)(i0 + 16 * qi) * lda + ko, lda,
          Vh + (size_t)(j0 + 16 * qj) * ldb + ko, Vl + (size_t)(j0 + 16 * qj) * ldb + ko, ldb,
          Kh, lm, lq, a1, a2);
    const f32x4 s = a1 + a2;
    #pragma unroll
    for (int r = 0; r < 4; ++r) red[w * 256 + (lq * 4 + r) * 16 + lm] = s[r];
    __syncthreads();
    #pragma unroll
    for (int e = 0; e < 2; ++e) {
        const int ee = t + e * 512;
        const int qq = ee >> 8, p = ee & 255;
        val[e] = red[qq * 512 + p] + red[qq * 512 + 256 + p];
        row[e] = i0 + 16 * (qq >> 1) + (p >> 4);
        col[e] = j0 + 16 * (qq & 1) + (p & 15);
    }
}

// ---- d1: X fp32 (D x M) -> Xhi/Xlo (row-major) + XThi/XTlo (M x D), LDS-tiled
__global__ __launch_bounds__(256) void trans_split(
    const float* __restrict__ X,
    u16* __restrict__ Xhi, u16* __restrict__ Xlo,
    u16* __restrict__ XThi, u16* __restrict__ XTlo) {
    __shared__ u16 Lh[64 * 72], Ll[64 * 72];
    const int dBase = blockIdx.x * 64;
    const int mBase = blockIdx.y * 64;
    const int t = threadIdx.x;
    const int dl = t >> 4;
    const int ml = (t & 15) * 4;
    #pragma unroll
    for (int i = 0; i < 4; ++i) {
        const int d = i * 16 + dl;
        const float4 v4 = *(const float4*)(X + (size_t)(dBase + d) * M + mBase + ml);
        const float v[4] = {v4.x, v4.y, v4.z, v4.w};
        u16 hi[4], lo[4];
        #pragma unroll
        for (int j = 0; j < 4; ++j) { hi[j] = f2bf(v[j]); lo[j] = f2bf(v[j] - bf2f(hi[j])); }
        *(uint2*)(Xhi + (size_t)(dBase + d) * M + mBase + ml) = pack4(hi);
        *(uint2*)(Xlo + (size_t)(dBase + d) * M + mBase + ml) = pack4(lo);
        #pragma unroll
        for (int j = 0; j < 4; ++j) { Lh[(ml + j) * 72 + d] = hi[j]; Ll[(ml + j) * 72 + d] = lo[j]; }
    }
    __syncthreads();
    const int m = t >> 2;
    const int dd = (t & 3) * 16;
    const uint4 h0 = *(const uint4*)(Lh + m * 72 + dd);
    const uint4 h1 = *(const uint4*)(Lh + m * 72 + dd + 8);
    const uint4 l0 = *(const uint4*)(Ll + m * 72 + dd);
    const uint4 l1 = *(const uint4*)(Ll + m * 72 + dd + 8);
    u16* th = XThi + (size_t)(mBase + m) * D + dBase + dd;
    u16* tl = XTlo + (size_t)(mBase + m) * D + dBase + dd;
    *(uint4*)th = h0; *(uint4*)(th + 8) = h1;
    *(uint4*)tl = l0; *(uint4*)(tl + 8) = l1;
}

// ---- d2: G0 = X^T X (32x32 tile/block, K=2048); emit G0, C1. grid 256 x 512 thr.
__global__ __launch_bounds__(512) void gram32(
    const u16* __restrict__ XThi, const u16* __restrict__ XTlo,
    u16* __restrict__ Gh, u16* __restrict__ Gl,
    u16* __restrict__ Ch, u16* __restrict__ Cl) {
    __shared__ float red[2048];
    const int i0 = (blockIdx.x >> 4) * 32, j0 = (blockIdx.x & 15) * 32;
    float val[2]; int row[2], col[2];
    tile32(XThi, XTlo, D, XThi, XTlo, D, 2048, i0, j0, threadIdx.x, red, val, row, col);
    #pragma unroll
    for (int e = 0; e < 2; ++e) {
        const size_t idx = (size_t)row[e] * M + col[e];
        const float g = val[e];
        u16 h = f2bf(g);
        Gh[idx] = h; Gl[idx] = f2bf(g - bf2f(h));
        const float c = (row[e] == col[e] ? CA1 : 0.0f) - CB1 * g;
        h = f2bf(c);
        Ch[idx] = h; Cl[idx] = f2bf(c - bf2f(h));
    }
}

// ---- plain M-space mm: O = U·V. grid 256 x 512 thr, 32x32 tile/block.
__global__ __launch_bounds__(512) void mm32(
    const u16* __restrict__ Uh, const u16* __restrict__ Ul,
    const u16* __restrict__ Vh, const u16* __restrict__ Vl,
    u16* __restrict__ Oh, u16* __restrict__ Ol) {
    __shared__ float red[2048];
    const int i0 = (blockIdx.x >> 4) * 32, j0 = (blockIdx.x & 15) * 32;
    float val[2]; int row[2], col[2];
    tile32(Uh, Ul, M, Vh, Vl, M, 512, i0, j0, threadIdx.x, red, val, row, col);
    #pragma unroll
    for (int e = 0; e < 2; ++e) {
        const size_t idx = (size_t)row[e] * M + col[e];
        const u16 h = f2bf(val[e]);
        Oh[idx] = h; Ol[idx] = f2bf(val[e] - bf2f(h));
    }
}

// ---- dual M-space mm: job0: O0=U0·V0, job1: O1=U1·V1. grid 512 x 512 thr.
__global__ __launch_bounds__(512) void dual32(
    const u16* __restrict__ U0h, const u16* __restrict__ U0l,
    const u16* __restrict__ V0h, const u16* __restrict__ V0l,
    u16* __restrict__ O0h, u16* __restrict__ O0l,
    const u16* __restrict__ U1h, const u16* __restrict__ U1l,
    const u16* __restrict__ V1h, const u16* __restrict__ V1l,
    u16* __restrict__ O1h, u16* __restrict__ O1l) {
    __shared__ float red[2048];
    const int job = blockIdx.x >> 8, tile = blockIdx.x & 255;
    const int i0 = (tile >> 4) * 32, j0 = (tile & 15) * 32;
    const u16* Uh = job ? U1h : U0h;
    const u16* Ul = job ? U1l : U0l;
    const u16* Vh = job ? V1h : V0h;
    const u16* Vl = job ? V1l : V0l;
    u16* Oh = job ? O1h : O0h;
    u16* Ol = job ? O1l : O0l;
    float val[2]; int row[2], col[2];
    tile32(Uh, Ul, M, Vh, Vl, M, 512, i0, j0, threadIdx.x, red, val, row, col);
    #pragma unroll
    for (int e = 0; e < 2; ++e) {
        const size_t idx = (size_t)row[e] * M + col[e];
        const u16 h = f2bf(val[e]);
        Oh[idx] = h; Ol[idx] = f2bf(val[e] - bf2f(h));
    }
}

// ---- poly step: W=U·V; P = cA*Ge + cB*Se + cC*W; store P (opt), C = a*I - b*P.
__global__ __launch_bounds__(512) void poly32(
    const u16* __restrict__ Uh, const u16* __restrict__ Ul,
    const u16* __restrict__ Vh, const u16* __restrict__ Vl,
    const u16* __restrict__ Geh, const u16* __restrict__ Gel,
    const u16* __restrict__ Seh, const u16* __restrict__ Sel,
    u16* __restrict__ Ph, u16* __restrict__ Pl,
    u16* __restrict__ Ch, u16* __restrict__ Cl,
    const float cA, const float cB, const float cC,
    const float a, const float b, const int writeP) {
    __shared__ float red[2048];
    const int i0 = (blockIdx.x >> 4) * 32, j0 = (blockIdx.x & 15) * 32;
    float val[2]; int row[2], col[2];
    tile32(Uh, Ul, M, Vh, Vl, M, 512, i0, j0, threadIdx.x, red, val, row, col);
    #pragma unroll
    for (int e = 0; e < 2; ++e) {
        const size_t idx = (size_t)row[e] * M + col[e];
        const float p = cA * (bf2f(Geh[idx]) + bf2f(Gel[idx]))
                      + cB * (bf2f(Seh[idx]) + bf2f(Sel[idx]))
                      + cC * val[e];
        if (writeP) {
            const u16 h = f2bf(p);
            Ph[idx] = h; Pl[idx] = f2bf(p - bf2f(h));
        }
        const float c = (row[e] == col[e] ? a : 0.0f) - b * p;
        const u16 h2 = f2bf(c);
        Ch[idx] = h2; Cl[idx] = f2bf(c - bf2f(h2));
    }
}

// ---- d8: out = X·B (fp32). 32x32 tile/block, 4 full-K quadrant waves.
// grid 1024 x 256 thr.
__global__ __launch_bounds__(256) void final32(
    const u16* __restrict__ Xhi, const u16* __restrict__ Xlo,
    const u16* __restrict__ Bh, const u16* __restrict__ Bl,
    float* __restrict__ out) {
    const int t = threadIdx.x;
    const int i0 = (blockIdx.x >> 4) * 32, j0 = (blockIdx.x & 15) * 32;
    const int w = t >> 6, lane = t & 63;
    const int lm = lane & 15, lq = lane >> 4;
    const int qi = w >> 1, qj = w & 1;
    f32x4 a1 = {0.f, 0.f, 0.f, 0.f}, a2 = {0.f, 0.f, 0.f, 0.f};
    mm_ks(Xhi + (size_t)(i0 + 16 * qi) * M, Xlo + (size_t)(i0 + 16 * qi) * M, M,
          Bh + (size_t)(j0 + 16 * qj) * M, Bl + (size_t)(j0 + 16 * qj) * M, M,
          512, lm, lq, a1, a2);
    const f32x4 acc = a1 + a2;
    float* o = out + (size_t)(i0 + 16 * qi + lq * 4) * M + j0 + 16 * qj + lm;
    #pragma unroll
    for (int r = 0; r < 4; ++r) o[(size_t)r * M] = acc[r];
}

extern "C" void kernel_launch(void* const* d_in, const int* in_sizes, int n_in,
                              void* d_out, int out_size, void* d_ws, size_t ws_size,
                              hipStream_t stream) {
    const float* Xin = (const float*)d_in[0];
    float* out = (float*)d_out;
    u16* w = (u16*)d_ws;

    u16* Xhi  = w;                   // D*M = 1048576 each
    u16* Xlo  = w + 1048576u;
    u16* XThi = w + 2097152u;
    u16* XTlo = w + 3145728u;
    u16* q = w + 4194304u;           // M*M = 262144 each below
    u16* G0h = q;            u16* G0l = q + 262144u;
    u16* Sh  = q + 524288u;  u16* Sl  = q + 786432u;
    u16* G1h = q + 1048576u; u16* G1l = q + 1310720u;
    u16* S1h = q + 1572864u; u16* S1l = q + 1835008u;
    u16* C1h = q + 2097152u; u16* C1l = q + 2359296u;
    u16* C2h = q + 2621440u; u16* C2l = q + 2883584u;
    u16* C3h = q + 3145728u; u16* C3l = q + 3407872u;
    u16* B2h = q + 3670016u; u16* B2l = q + 3932160u;
    u16* B3h = q + 4194304u; u16* B3l = q + 4456448u;

    // d1: split + transpose
    trans_split<<<dim3(32, 8), 256, 0, stream>>>(Xin, Xhi, Xlo, XThi, XTlo);
    // d2: G0 = X^T X ; C1 = CA1 I - CB1 G0
    gram32<<<256, 512, 0, stream>>>(XThi, XTlo, G0h, G0l, C1h, C1l);
    // d3: S = G0^2
    mm32<<<256, 512, 0, stream>>>(G0h, G0l, G0h, G0l, Sh, Sl);
    // d4: G1 = CA1^2 G0 - 2 CA1 CB1 S + CB1^2 (G0·S) ; C2 = CA2 I - CB2 G1
    poly32<<<256, 512, 0, stream>>>(G0h, G0l, Sh, Sl, G0h, G0l, Sh, Sl,
                                    G1h, G1l, C2h, C2l,
                                    CA1 * CA1, -2.0f * CA1 * CB1, CB1 * CB1,
                                    CA2, CB2, 1);
    // d5: S1 = G1^2  ||  B2 = C1·C2
    dual32<<<512, 512, 0, stream>>>(G1h, G1l, G1h, G1l, S1h, S1l,
                                    C1h, C1l, C2h, C2l, B2h, B2l);
    // d6: G2-poly -> C3 only
    poly32<<<256, 512, 0, stream>>>(G1h, G1l, S1h, S1l, G1h, G1l, S1h, S1l,
                                    nullptr, nullptr, C3h, C3l,
                                    CA2 * CA2, -2.0f * CA2 * CB2, CB2 * CB2,
                                    CA3, CB3, 0);
    // d7: B3 = B2·C3
    mm32<<<256, 512, 0, stream>>>(B2h, B2l, C3h, C3l, B3h, B3l);
    // d8: out = X·B3
    final32<<<1024, 256, 0, stream>>>(Xhi, Xlo, B3h, B3l, out);
}

// Round 12
// 161.765 us; speedup vs baseline: 1.1905x; 1.0726x over previous
//
#include <hip/hip_runtime.h>

#define D 2048
#define M 512

// Tuned NS coefficients, equioscillation on sv interval [0.48,1.52]:
// step1 -> delta 0.2188, step2 -> 0.03633, step3 -> 0.00099
#define CA1 1.7509363f
#define CB1 0.5353890f
#define CA2 1.5424421f
#define CB2 0.5060067f
#define CA3 1.5011558f
#define CB3 0.5001653f

typedef unsigned short u16;
typedef unsigned int u32;
typedef __attribute__((ext_vector_type(8))) short bf16x8;
typedef __attribute__((ext_vector_type(4))) float f32x4;

__device__ inline u16 f2bf(float f) {
    union { float f; unsigned u; } v; v.f = f;
    unsigned r = v.u + 0x7fffu + ((v.u >> 16) & 1u);  // RNE
    return (u16)(r >> 16);
}
__device__ inline float bf2f(u16 h) {
    union { float f; unsigned u; } v; v.u = ((unsigned)h) << 16;
    return v.f;
}

// per-wave K-range fragment MACs into acc pair (split-bf16 3-MFMA scheme)
__device__ inline void mm_ks(const u16* __restrict__ aHi,
                             const u16* __restrict__ aLo, int lda,
                             const u16* __restrict__ bHi,
                             const u16* __restrict__ bLo, int ldb,
                             int K, int lm, int lq, f32x4& a1, f32x4& a2) {
    const u16* ah = aHi + (size_t)lm * lda + lq * 8;
    const u16* al = aLo + (size_t)lm * lda + lq * 8;
    const u16* bh = bHi + (size_t)lm * ldb + lq * 8;
    const u16* bl = bLo + (size_t)lm * ldb + lq * 8;
    #pragma unroll 4
    for (int k = 0; k < K; k += 32) {
        const bf16x8 fah = *(const bf16x8*)(ah + k);
        const bf16x8 fal = *(const bf16x8*)(al + k);
        const bf16x8 fbh = *(const bf16x8*)(bh + k);
        const bf16x8 fbl = *(const bf16x8*)(bl + k);
        a1 = __builtin_amdgcn_mfma_f32_16x16x32_bf16(fah, fbh, a1, 0, 0, 0);
        a2 = __builtin_amdgcn_mfma_f32_16x16x32_bf16(fah, fbl, a2, 0, 0, 0);
        a2 = __builtin_amdgcn_mfma_f32_16x16x32_bf16(fal, fbh, a2, 0, 0, 0);
    }
}

// 32x32 tile of U·V per 512-thread block: 8 waves = 4 quadrants x 2 K-halves.
__device__ inline void tile32(const u16* __restrict__ Uh, const u16* __restrict__ Ul, int lda,
                              const u16* __restrict__ Vh, const u16* __restrict__ Vl, int ldb,
                              int K, int i0, int j0, int t, float* red,
                              float val[2], int row[2], int col[2]) {
    const int w = t >> 6, lane = t & 63;
    const int lm = lane & 15, lq = lane >> 4;
    const int q = w >> 1, kh = w & 1;
    const int qi = q >> 1, qj = q & 1;
    const int Kh = K >> 1;
    const size_t ko = (size_t)kh * Kh;
    f32x4 a1 = {0.f, 0.f, 0.f, 0.f}, a2 = {0.f, 0.f, 0.f, 0.f};
    mm_ks(Uh + (size_t)(i0 + 16 * qi) * lda + ko, Ul + (size_t)(i0 + 16 * qi) * lda + ko, lda,
          Vh + (size_t)(j0 + 16 * qj) * ldb + ko, Vl + (size_t)(j0 + 16 * qj) * ldb + ko, ldb,
          Kh, lm, lq, a1, a2);
    const f32x4 s = a1 + a2;
    #pragma unroll
    for (int r = 0; r < 4; ++r) red[w * 256 + (lq * 4 + r) * 16 + lm] = s[r];
    __syncthreads();
    #pragma unroll
    for (int e = 0; e < 2; ++e) {
        const int ee = t + e * 512;
        const int qq = ee >> 8, p = ee & 255;
        val[e] = red[qq * 512 + p] + red[qq * 512 + 256 + p];
        row[e] = i0 + 16 * (qq >> 1) + (p >> 4);
        col[e] = j0 + 16 * (qq & 1) + (p & 15);
    }
}

// LDS swizzle for the fused gram staging
__device__ inline int swz(int c) { return (((c >> 2) ^ c) & 3) << 3; }

// ---- d1: fused transpose + gram: G0 = X^T X from X fp32 directly.
// 256 blocks x 512 thr. Staging: per 64-k chunk, both column-stripes are
// loaded as float4, split into (hi<<16)|lo u32, stored LDS-transposed
// [c][k^swz(c)]. 8 waves = 4 quadrants x 2 k-halves, one MFMA k-step/iter.
// Blocks with j0==0 also emit Xhi/Xlo row-major (they cover all of X).
// Emits G0 hi/lo and C1 = CA1*I - CB1*G0.
__global__ __launch_bounds__(512) void gram_fx(
    const float* __restrict__ X,
    u16* __restrict__ Gh, u16* __restrict__ Gl,
    u16* __restrict__ Ch, u16* __restrict__ Cl,
    u16* __restrict__ Xhi, u16* __restrict__ Xlo) {
    __shared__ __align__(16) char smem[32768];
    u32* LT = (u32*)smem;          // 4 regions of 2048 u32: (side*2+buf)*2048
    float* red = (float*)smem;     // reused for the final reduce

    const int i0 = (blockIdx.x >> 4) * 32, j0 = (blockIdx.x & 15) * 32;
    const int t = threadIdx.x;
    const int w = t >> 6, lane = t & 63;
    const int lm = lane & 15, lq = lane >> 4;
    const int q = w >> 1, kh = w & 1;
    const int qi = q >> 1, qj = q & 1;
    const bool emitX = (j0 == 0);

    const int r = t >> 3;            // 0..63 (k within chunk)
    const int c4 = (t & 7) * 4;      // 0..28 (col within stripe)

    const float* pa = X + (size_t)r * M + i0 + c4;
    const float* pb = X + (size_t)r * M + j0 + c4;
    float4 fA = *(const float4*)pa;
    float4 fB = *(const float4*)pb;

    f32x4 a1 = {0.f, 0.f, 0.f, 0.f}, a2 = {0.f, 0.f, 0.f, 0.f};
    int buf = 0;

    for (int k0 = 0; k0 < D; k0 += 64) {
        // split current chunk into packed u32 and stage transposed
        u32 pkA[4], pkB[4];
        {
            const float va[4] = {fA.x, fA.y, fA.z, fA.w};
            const float vb[4] = {fB.x, fB.y, fB.z, fB.w};
            #pragma unroll
            for (int e = 0; e < 4; ++e) {
                union { float f; u32 u; } ua, ub, ha, hb;
                ua.f = va[e]; ub.f = vb[e];
                ha.u = ua.u & 0xFFFF0000u;      // truncated hi
                hb.u = ub.u & 0xFFFF0000u;
                pkA[e] = ha.u | f2bf(va[e] - ha.f);
                pkB[e] = hb.u | f2bf(vb[e] - hb.f);
            }
        }
        u32* A0 = LT + (0 * 2 + buf) * 2048;
        u32* B0 = LT + (2 + buf) * 2048;
        #pragma unroll
        for (int e = 0; e < 4; ++e) {
            const int c = c4 + e;
            A0[c * 64 + (r ^ swz(c))] = pkA[e];
            B0[c * 64 + (r ^ swz(c))] = pkB[e];
        }
        if (emitX) {  // row-major bf16 split of X (this block's A-stripe)
            uint2 hw, lw;
            hw.x = (pkA[0] >> 16) | (pkA[1] & 0xFFFF0000u);
            hw.y = (pkA[2] >> 16) | (pkA[3] & 0xFFFF0000u);
            lw.x = (pkA[0] & 0xFFFFu) | (pkA[1] << 16);
            lw.y = (pkA[2] & 0xFFFFu) | (pkA[3] << 16);
            *(uint2*)(Xhi + (size_t)(k0 + r) * M + i0 + c4) = hw;
            *(uint2*)(Xlo + (size_t)(k0 + r) * M + i0 + c4) = lw;
        }
        __syncthreads();
        // prefetch next chunk
        if (k0 + 64 < D) {
            fA = *(const float4*)(pa + (size_t)(k0 + 64) * M);
            fB = *(const float4*)(pb + (size_t)(k0 + 64) * M);
        }
        // fragments: c = 16*q? + lm, k = kh*32 + lq*8 .. +8
        {
            const int ca = 16 * qi + lm, cb = 16 * qj + lm;
            const int kb = kh * 32 + lq * 8;
            const u32* ap = A0 + ca * 64 + (kb ^ swz(ca));
            const u32* bp = B0 + cb * 64 + (kb ^ swz(cb));
            u32 au[8], bu[8];
            *(uint4*)(au) = *(const uint4*)(ap);
            *(uint4*)(au + 4) = *(const uint4*)(ap + 4);
            *(uint4*)(bu) = *(const uint4*)(bp);
            *(uint4*)(bu + 4) = *(const uint4*)(bp + 4);
            u32 ahp[4], alp[4], bhp[4], blp[4];
            #pragma unroll
            for (int e = 0; e < 4; ++e) {
                ahp[e] = (au[2 * e] >> 16) | (au[2 * e + 1] & 0xFFFF0000u);
                alp[e] = (au[2 * e] & 0xFFFFu) | (au[2 * e + 1] << 16);
                bhp[e] = (bu[2 * e] >> 16) | (bu[2 * e + 1] & 0xFFFF0000u);
                blp[e] = (bu[2 * e] & 0xFFFFu) | (bu[2 * e + 1] << 16);
            }
            const bf16x8 fah = *(const bf16x8*)ahp;
            const bf16x8 fal = *(const bf16x8*)alp;
            const bf16x8 fbh = *(const bf16x8*)bhp;
            const bf16x8 fbl = *(const bf16x8*)blp;
            a1 = __builtin_amdgcn_mfma_f32_16x16x32_bf16(fah, fbh, a1, 0, 0, 0);
            a2 = __builtin_amdgcn_mfma_f32_16x16x32_bf16(fah, fbl, a2, 0, 0, 0);
            a2 = __builtin_amdgcn_mfma_f32_16x16x32_bf16(fal, fbh, a2, 0, 0, 0);
        }
        buf ^= 1;
    }

    // reduce k-halves and emit G0, C1
    __syncthreads();
    const f32x4 s = a1 + a2;
    #pragma unroll
    for (int e = 0; e < 4; ++e) red[w * 256 + (lq * 4 + e) * 16 + lm] = s[e];
    __syncthreads();
    #pragma unroll
    for (int e = 0; e < 2; ++e) {
        const int ee = t + e * 512;
        const int qq = ee >> 8, p = ee & 255;
        const float g = red[qq * 512 + p] + red[qq * 512 + 256 + p];
        const int row = i0 + 16 * (qq >> 1) + (p >> 4);
        const int col = j0 + 16 * (qq & 1) + (p & 15);
        const size_t idx = (size_t)row * M + col;
        u16 h = f2bf(g);
        Gh[idx] = h; Gl[idx] = f2bf(g - bf2f(h));
        const float c = (row == col ? CA1 : 0.0f) - CB1 * g;
        h = f2bf(c);
        Ch[idx] = h; Cl[idx] = f2bf(c - bf2f(h));
    }
}

// ---- plain M-space mm: O = U·V. grid 256 x 512 thr, 32x32 tile/block.
__global__ __launch_bounds__(512) void mm32(
    const u16* __restrict__ Uh, const u16* __restrict__ Ul,
    const u16* __restrict__ Vh, const u16* __restrict__ Vl,
    u16* __restrict__ Oh, u16* __restrict__ Ol) {
    __shared__ float red[2048];
    const int i0 = (blockIdx.x >> 4) * 32, j0 = (blockIdx.x & 15) * 32;
    float val[2]; int row[2], col[2];
    tile32(Uh, Ul, M, Vh, Vl, M, 512, i0, j0, threadIdx.x, red, val, row, col);
    #pragma unroll
    for (int e = 0; e < 2; ++e) {
        const size_t idx = (size_t)row[e] * M + col[e];
        const u16 h = f2bf(val[e]);
        Oh[idx] = h; Ol[idx] = f2bf(val[e] - bf2f(h));
    }
}

// ---- dual M-space mm: job0: O0=U0·V0, job1: O1=U1·V1. grid 512 x 512 thr.
__global__ __launch_bounds__(512) void dual32(
    const u16* __restrict__ U0h, const u16* __restrict__ U0l,
    const u16* __restrict__ V0h, const u16* __restrict__ V0l,
    u16* __restrict__ O0h, u16* __restrict__ O0l,
    const u16* __restrict__ U1h, const u16* __restrict__ U1l,
    const u16* __restrict__ V1h, const u16* __restrict__ V1l,
    u16* __restrict__ O1h, u16* __restrict__ O1l) {
    __shared__ float red[2048];
    const int job = blockIdx.x >> 8, tile = blockIdx.x & 255;
    const int i0 = (tile >> 4) * 32, j0 = (tile & 15) * 32;
    const u16* Uh = job ? U1h : U0h;
    const u16* Ul = job ? U1l : U0l;
    const u16* Vh = job ? V1h : V0h;
    const u16* Vl = job ? V1l : V0l;
    u16* Oh = job ? O1h : O0h;
    u16* Ol = job ? O1l : O0l;
    float val[2]; int row[2], col[2];
    tile32(Uh, Ul, M, Vh, Vl, M, 512, i0, j0, threadIdx.x, red, val, row, col);
    #pragma unroll
    for (int e = 0; e < 2; ++e) {
        const size_t idx = (size_t)row[e] * M + col[e];
        const u16 h = f2bf(val[e]);
        Oh[idx] = h; Ol[idx] = f2bf(val[e] - bf2f(h));
    }
}

// ---- poly step: W=U·V; P = cA*Ge + cB*Se + cC*W; store P (opt), C = a*I - b*P.
__global__ __launch_bounds__(512) void poly32(
    const u16* __restrict__ Uh, const u16* __restrict__ Ul,
    const u16* __restrict__ Vh, const u16* __restrict__ Vl,
    const u16* __restrict__ Geh, const u16* __restrict__ Gel,
    const u16* __restrict__ Seh, const u16* __restrict__ Sel,
    u16* __restrict__ Ph, u16* __restrict__ Pl,
    u16* __restrict__ Ch, u16* __restrict__ Cl,
    const float cA, const float cB, const float cC,
    const float a, const float b, const int writeP) {
    __shared__ float red[2048];
    const int i0 = (blockIdx.x >> 4) * 32, j0 = (blockIdx.x & 15) * 32;
    float val[2]; int row[2], col[2];
    tile32(Uh, Ul, M, Vh, Vl, M, 512, i0, j0, threadIdx.x, red, val, row, col);
    #pragma unroll
    for (int e = 0; e < 2; ++e) {
        const size_t idx = (size_t)row[e] * M + col[e];
        const float p = cA * (bf2f(Geh[idx]) + bf2f(Gel[idx]))
                      + cB * (bf2f(Seh[idx]) + bf2f(Sel[idx]))
                      + cC * val[e];
        if (writeP) {
            const u16 h = f2bf(p);
            Ph[idx] = h; Pl[idx] = f2bf(p - bf2f(h));
        }
        const float c = (row[e] == col[e] ? a : 0.0f) - b * p;
        const u16 h2 = f2bf(c);
        Ch[idx] = h2; Cl[idx] = f2bf(c - bf2f(h2));
    }
}

// ---- d7: out = X·B (fp32). 32x32 tile/block, 4 full-K quadrant waves.
__global__ __launch_bounds__(256) void final32(
    const u16* __restrict__ Xhi, const u16* __restrict__ Xlo,
    const u16* __restrict__ Bh, const u16* __restrict__ Bl,
    float* __restrict__ out) {
    const int t = threadIdx.x;
    const int i0 = (blockIdx.x >> 4) * 32, j0 = (blockIdx.x & 15) * 32;
    const int w = t >> 6, lane = t & 63;
    const int lm = lane & 15, lq = lane >> 4;
    const int qi = w >> 1, qj = w & 1;
    f32x4 a1 = {0.f, 0.f, 0.f, 0.f}, a2 = {0.f, 0.f, 0.f, 0.f};
    mm_ks(Xhi + (size_t)(i0 + 16 * qi) * M, Xlo + (size_t)(i0 + 16 * qi) * M, M,
          Bh + (size_t)(j0 + 16 * qj) * M, Bl + (size_t)(j0 + 16 * qj) * M, M,
          512, lm, lq, a1, a2);
    const f32x4 acc = a1 + a2;
    float* o = out + (size_t)(i0 + 16 * qi + lq * 4) * M + j0 + 16 * qj + lm;
    #pragma unroll
    for (int r = 0; r < 4; ++r) o[(size_t)r * M] = acc[r];
}

extern "C" void kernel_launch(void* const* d_in, const int* in_sizes, int n_in,
                              void* d_out, int out_size, void* d_ws, size_t ws_size,
                              hipStream_t stream) {
    const float* Xin = (const float*)d_in[0];
    float* out = (float*)d_out;
    u16* w = (u16*)d_ws;

    u16* Xhi  = w;                   // D*M = 1048576 each
    u16* Xlo  = w + 1048576u;
    u16* q = w + 2097152u;           // M*M = 262144 each below
    u16* G0h = q;            u16* G0l = q + 262144u;
    u16* Sh  = q + 524288u;  u16* Sl  = q + 786432u;
    u16* G1h = q + 1048576u; u16* G1l = q + 1310720u;
    u16* S1h = q + 1572864u; u16* S1l = q + 1835008u;
    u16* C1h = q + 2097152u; u16* C1l = q + 2359296u;
    u16* C2h = q + 2621440u; u16* C2l = q + 2883584u;
    u16* C3h = q + 3145728u; u16* C3l = q + 3407872u;
    u16* B2h = q + 3670016u; u16* B2l = q + 3932160u;
    u16* B3h = q + 4194304u; u16* B3l = q + 4456448u;

    // d1: fused transpose + gram: G0, C1, Xhi/Xlo
    gram_fx<<<256, 512, 0, stream>>>(Xin, G0h, G0l, C1h, C1l, Xhi, Xlo);
    // d2: S = G0^2
    mm32<<<256, 512, 0, stream>>>(G0h, G0l, G0h, G0l, Sh, Sl);
    // d3: G1 = CA1^2 G0 - 2 CA1 CB1 S + CB1^2 (G0·S) ; C2 = CA2 I - CB2 G1
    poly32<<<256, 512, 0, stream>>>(G0h, G0l, Sh, Sl, G0h, G0l, Sh, Sl,
                                    G1h, G1l, C2h, C2l,
                                    CA1 * CA1, -2.0f * CA1 * CB1, CB1 * CB1,
                                    CA2, CB2, 1);
    // d4: S1 = G1^2  ||  B2 = C1·C2
    dual32<<<512, 512, 0, stream>>>(G1h, G1l, G1h, G1l, S1h, S1l,
                                    C1h, C1l, C2h, C2l, B2h, B2l);
    // d5: G2-poly -> C3 only
    poly32<<<256, 512, 0, stream>>>(G1h, G1l, S1h, S1l, G1h, G1l, S1h, S1l,
                                    nullptr, nullptr, C3h, C3l,
                                    CA2 * CA2, -2.0f * CA2 * CB2, CB2 * CB2,
                                    CA3, CB3, 0);
    // d6: B3 = B2·C3
    mm32<<<256, 512, 0, stream>>>(B2h, B2l, C3h, C3l, B3h, B3l);
    // d7: out = X·B3
    final32<<<1024, 256, 0, stream>>>(Xhi, Xlo, B3h, B3l, out);
}